// Round 24
// baseline (48.355 us; speedup 1.0000x reference)
//
#include <hip/hip_runtime.h>
#include <hip/hip_bf16.h>

#define NB   4
#define CIN  64
#define COUT 64
#define HH   160
#define WW   160
#define HW   (HH * WW)

// halo tile: 2x16 output tile, rate in [1,3) =>
// rows 2rr-3 .. 2rr+4 (8), cols 16cc-3 .. 16cc+18 (22).
#define RT   8
#define CT   22
#define RS   72              // record stride in shorts (144 B: 64ch + 8 pad)
#define RSB  (RS * 2)        // record stride in bytes (144)
#define HIN_SHORTS (RT * CT * RS)   // 12672 shorts = 25344 B

typedef __attribute__((ext_vector_type(8))) short bf16x8;   // 8 bf16 = 4 VGPR
typedef __attribute__((ext_vector_type(4))) float f32x4;
typedef __attribute__((ext_vector_type(2))) float f32x2;
typedef __attribute__((ext_vector_type(4))) unsigned int u32x4;

static __device__ __forceinline__ short f2bf(float v) {
    return __builtin_bit_cast(short, __float2bfloat16(v));
}

// ---------------------------------------------------------------------------
// Pre-pass 1: weight [O][C][3][3] f32 -> wtf in exact A-fragment order.
// ---------------------------------------------------------------------------
__global__ void wtf_kernel(const float* __restrict__ w, short* __restrict__ wtf) {
    int i = blockIdx.x * 256 + threadIdx.x;   // 9*2*4*64*8 = 36864
    if (i < 36864) {
        const int j  = i & 7;
        const int l  = (i >> 3) & 63;
        const int mt = (i >> 9) & 3;
        const int ks = (i >> 11) & 1;
        const int t  = i >> 12;
        const int o  = 16 * mt + (l & 15);
        const int c  = 32 * ks + 8 * (l >> 4) + j;
        wtf[i] = f2bf(w[(o * CIN + c) * 9 + t]);
    }
}

// ---------------------------------------------------------------------------
// Pre-pass 2: input [B][C][H][W] f32 -> tin [B][H][W][C] bf16 (XCD-aligned).
// ---------------------------------------------------------------------------
__global__ __launch_bounds__(256) void tin_kernel(const float* __restrict__ in,
                                                  short* __restrict__ tin) {
    const int cpx = gridDim.x >> 3;
    const int wb  = (blockIdx.x & 7) * cpx + (blockIdx.x >> 3);
    const int gid = wb * 256 + threadIdx.x;
    if (gid >= NB * HW) return;
    const int b  = gid / HW;
    const int hw = gid - b * HW;
    const float* src = in + (size_t)b * CIN * HW + hw;
    short* dst = tin + (size_t)gid * CIN;
#pragma unroll
    for (int chunk = 0; chunk < 4; ++chunk) {
        union { u32x4 v; short s[8]; } p0, p1;
#pragma unroll
        for (int cc = 0; cc < 8; ++cc)
            p0.s[cc] = f2bf(src[(size_t)(chunk * 16 + cc) * HW]);
#pragma unroll
        for (int cc = 0; cc < 8; ++cc)
            p1.s[cc] = f2bf(src[(size_t)(chunk * 16 + 8 + cc) * HW]);
        *(u32x4*)(dst + chunk * 16)     = p0.v;
        *(u32x4*)(dst + chunk * 16 + 8) = p1.v;
    }
}

// Blend 8 channels (4 dwords of packed bf16 pairs) + 4 MFMA rank-updates.
static __device__ __forceinline__ void consume_tap(
    const u32x4 v00, const u32x4 v01, const u32x4 v10, const u32x4 v11,
    const float c00, const float c01, const float c10, const float c11,
    const bf16x8 wf0, const bf16x8 wf1, const bf16x8 wf2, const bf16x8 wf3,
    f32x4 acc[4])
{
    union { bf16x8 v; unsigned u[4]; } pf;
#pragma unroll
    for (int wd = 0; wd < 4; ++wd) {
        f32x2 s;
        {
            const unsigned u0 = v00[wd];
            const f32x2 xv = { __builtin_bit_cast(float, u0 << 16),
                               __builtin_bit_cast(float, u0 & 0xffff0000u) };
            s = c00 * xv;
        }
        {
            const unsigned u0 = v01[wd];
            const f32x2 xv = { __builtin_bit_cast(float, u0 << 16),
                               __builtin_bit_cast(float, u0 & 0xffff0000u) };
            s += c01 * xv;
        }
        {
            const unsigned u0 = v10[wd];
            const f32x2 xv = { __builtin_bit_cast(float, u0 << 16),
                               __builtin_bit_cast(float, u0 & 0xffff0000u) };
            s += c10 * xv;
        }
        {
            const unsigned u0 = v11[wd];
            const f32x2 xv = { __builtin_bit_cast(float, u0 << 16),
                               __builtin_bit_cast(float, u0 & 0xffff0000u) };
            s += c11 * xv;
        }
        unsigned r;
        asm("v_cvt_pk_bf16_f32 %0, %1, %2" : "=v"(r) : "v"(s.x), "v"(s.y));
        pf.u[wd] = r;
    }
    acc[0] = __builtin_amdgcn_mfma_f32_16x16x32_bf16(wf0, pf.v, acc[0], 0, 0, 0);
    acc[1] = __builtin_amdgcn_mfma_f32_16x16x32_bf16(wf1, pf.v, acc[1], 0, 0, 0);
    acc[2] = __builtin_amdgcn_mfma_f32_16x16x32_bf16(wf2, pf.v, acc[2], 0, 0, 0);
    acc[3] = __builtin_amdgcn_mfma_f32_16x16x32_bf16(wf3, pf.v, acc[3], 0, 0, 0);
}

// ---------------------------------------------------------------------------
// Main kernel (R23 structure + INLINE-ASM LDS PIPELINE): block = 2x16 tile,
// 4 waves = 2 rows x 2 K-halves, hoisted separable geometry (R23-verified).
// The tap loop is software-pipelined AT THE INSTRUCTION LEVEL: tap t+1's
// 4 ds_read_b128 are issued as volatile asm (cannot be sunk — 4 compiler-
// level attempts R15/16/17/21 all collapsed), then s_waitcnt lgkmcnt(4)
// waits only for tap t's data (t+1's reads stay in flight across the
// blend), then sched_barrier(0) stops VALU/MFMA hoisting past the wait
// (rule #18). All 4 corners share one address VGPR via offset: immediates
// (0 / 144 / 3168 / 3312). Two register slots (A/B) alternate.
// ---------------------------------------------------------------------------
__global__ __launch_bounds__(256, 4) void pdconv_tile_kernel(
    const short* __restrict__ tin,       // [B][H][W][CIN] bf16
    const short* __restrict__ wtf,       // frag-ordered weights bf16
    const float* __restrict__ rate_map,  // [B][1][H][W] f32
    const float* __restrict__ bias,      // [COUT] f32
    float* __restrict__ out)             // [B][COUT][H][W] f32
{
    __shared__ short hin[HIN_SHORTS];    // 25,344 B
    __shared__ float red[2][64][17];     // 8,704 B

    const int tid  = threadIdx.x;
    const int wave = tid >> 6;
    const int lane = tid & 63;
    const int px   = lane & 15;
    const int g    = lane >> 4;
    const int r    = wave >> 1;          // row within the 2-row tile
    const int th   = wave & 1;           // channel half (ks)

    // XCD-bijective swizzle (3200 % 8 == 0)
    const int cpx = gridDim.x >> 3;                     // 400
    const int bid = (blockIdx.x & 7) * cpx + (blockIdx.x >> 3);

    const int b   = bid / 800;
    const int rem = bid - b * 800;
    const int rr  = rem / 10;
    const int cc  = rem - rr * 10;
    const int oy  = 2 * rr - 3;
    const int ox  = 16 * cc - 3;

    // ---- stage halo tile -> LDS (coalesced; edges clamped) ----
    const short* ib = tin + (size_t)b * HW * CIN;
#pragma unroll
    for (int it = 0; it < 6; ++it) {
        const int idx = it * 256 + tid;
        if (idx < RT * CT * 8) {
            const int rec = idx >> 3;
            const int cp  = idx & 7;
            const int ty  = rec / CT;
            const int tx  = rec - ty * CT;
            const int gy  = min(max(oy + ty, 0), HH - 1);
            const int gx  = min(max(ox + tx, 0), WW - 1);
            const u32x4 v = *(const u32x4*)(ib + ((size_t)gy * WW + gx) * CIN + cp * 8);
            *(u32x4*)(hin + rec * RS + cp * 8) = v;
        }
    }

    // ---- per-wave output strip ----
    const int row = 2 * rr + r;
    const int x   = 16 * cc + px;
    const float rate = rate_map[b * HW + row * WW + x];
    const float fy = (float)row, fx = (float)x;

    // ---- hoisted separable geometry (R23-verified incl. >=0 checks) ----
    float wy0v[3], wy1v[3];  int ryb[3];
#pragma unroll
    for (int ky = 0; ky < 3; ++ky) {
        const float sy  = fy + (float)(ky - 1) * rate;
        const float y0f = floorf(sy);
        const float wy  = sy - y0f;
        const int   y0  = (int)y0f;
        const float vy0 = (y0 >= 0 && y0 < HH) ? 1.0f : 0.0f;
        const float vy1 = (y0 + 1 >= 0 && y0 + 1 < HH) ? 1.0f : 0.0f;
        wy0v[ky] = (1.0f - wy) * vy0;
        wy1v[ky] = wy * vy1;
        ryb[ky]  = (y0 - oy) * (CT * RSB);
    }
    float wx0v[3], wx1v[3];  int txb[3];
#pragma unroll
    for (int kx = 0; kx < 3; ++kx) {
        const float sx  = fx + (float)(kx - 1) * rate;
        const float x0f = floorf(sx);
        const float wx  = sx - x0f;
        const int   x0  = (int)x0f;
        const float vx0 = (x0 >= 0 && x0 < WW) ? 1.0f : 0.0f;
        const float vx1 = (x0 + 1 >= 0 && x0 + 1 < WW) ? 1.0f : 0.0f;
        wx0v[kx] = (1.0f - wx) * vx0;
        wx1v[kx] = wx * vx1;
        txb[kx]  = (x0 - ox) * RSB;
    }

    const int chan_byte = (32 * th + 8 * g) * 2;

    // 9 tap LDS byte addresses (32-bit LDS offset = truncated flat addr;
    // shared aperture low 32 bits are 0 on gfx9 — HipKittens pattern)
    const unsigned ldsb = (unsigned)(size_t)(const void*)hin + (unsigned)chan_byte;
    unsigned hkb[9];
#pragma unroll
    for (int t = 0; t < 9; ++t) {
        const int ky = t / 3, kx = t - 3 * (t / 3);
        hkb[t] = ldsb + (unsigned)(ryb[ky] + txb[kx]);
    }

    const short* wtb = wtf + lane * 8;

    f32x4 acc[4];
#pragma unroll
    for (int mt = 0; mt < 4; ++mt) acc[mt] = (f32x4){0.f, 0.f, 0.f, 0.f};

    u32x4 sA0, sA1, sA2, sA3, sB0, sB1, sB2, sB3;

    // 4 corner reads from one address VGPR: +0, +144 (x+1), +3168 (y+1),
    // +3312 (y+1,x+1) byte immediates.
#define ISSUE(T, S0, S1, S2, S3)                                             \
    asm volatile("ds_read_b128 %0, %4\n\t"                                   \
                 "ds_read_b128 %1, %4 offset:144\n\t"                        \
                 "ds_read_b128 %2, %4 offset:3168\n\t"                       \
                 "ds_read_b128 %3, %4 offset:3312"                           \
                 : "=&v"(S0), "=&v"(S1), "=&v"(S2), "=&v"(S3)                \
                 : "v"(hkb[T]))

#define LWAIT(N)                                                             \
    asm volatile("s_waitcnt lgkmcnt(" #N ")" ::: "memory");                  \
    __builtin_amdgcn_sched_barrier(0)

#define CONSUME(T, S0, S1, S2, S3) do {                                      \
    const int ky = (T) / 3, kx = (T) - 3 * ((T) / 3);                        \
    const float c00 = wy0v[ky] * wx0v[kx];                                   \
    const float c01 = wy0v[ky] * wx1v[kx];                                   \
    const float c10 = wy1v[ky] * wx0v[kx];                                   \
    const float c11 = wy1v[ky] * wx1v[kx];                                   \
    const short* wb = wtb + (size_t)(((T) * 2 + th) * 4) * 512;              \
    const bf16x8 wf0 = *(const bf16x8*)(wb);                                 \
    const bf16x8 wf1 = *(const bf16x8*)(wb + 512);                           \
    const bf16x8 wf2 = *(const bf16x8*)(wb + 1024);                          \
    const bf16x8 wf3 = *(const bf16x8*)(wb + 1536);                          \
    consume_tap(S0, S1, S2, S3, c00, c01, c10, c11,                          \
                wf0, wf1, wf2, wf3, acc);                                    \
} while (0)

    __syncthreads();                     // halo staged
    ISSUE(0, sA0, sA1, sA2, sA3);        // prologue: tap-0 reads

    ISSUE(1, sB0, sB1, sB2, sB3); LWAIT(4); CONSUME(0, sA0, sA1, sA2, sA3);
    ISSUE(2, sA0, sA1, sA2, sA3); LWAIT(4); CONSUME(1, sB0, sB1, sB2, sB3);
    ISSUE(3, sB0, sB1, sB2, sB3); LWAIT(4); CONSUME(2, sA0, sA1, sA2, sA3);
    ISSUE(4, sA0, sA1, sA2, sA3); LWAIT(4); CONSUME(3, sB0, sB1, sB2, sB3);
    ISSUE(5, sB0, sB1, sB2, sB3); LWAIT(4); CONSUME(4, sA0, sA1, sA2, sA3);
    ISSUE(6, sA0, sA1, sA2, sA3); LWAIT(4); CONSUME(5, sB0, sB1, sB2, sB3);
    ISSUE(7, sB0, sB1, sB2, sB3); LWAIT(4); CONSUME(6, sA0, sA1, sA2, sA3);
    ISSUE(8, sA0, sA1, sA2, sA3); LWAIT(4); CONSUME(7, sB0, sB1, sB2, sB3);
    LWAIT(0);                     CONSUME(8, sA0, sA1, sA2, sA3);

#undef ISSUE
#undef LWAIT
#undef CONSUME

    // ---- channel-half reduction via dedicated red buffer ----
    if (th == 1) {
#pragma unroll
        for (int mt = 0; mt < 4; ++mt)
#pragma unroll
            for (int j = 0; j < 4; ++j)
                red[r][lane][4 * mt + j] = acc[mt][j];
    }
    __syncthreads();
    if (th == 0) {
        float* op = out + (size_t)b * COUT * HW + row * WW + 16 * cc + px;
#pragma unroll
        for (int mt = 0; mt < 4; ++mt) {
            const f32x4 bv = *(const f32x4*)(bias + 16 * mt + 4 * g);
#pragma unroll
            for (int j = 0; j < 4; ++j) {
                const int o = 16 * mt + 4 * g + j;
                op[(size_t)o * HW] = acc[mt][j] + red[r][lane][4 * mt + j]
                                   + bv[j];
            }
        }
    }
}

// ---------------------------------------------------------------------------
// Fallback (round-7 NCHW path) if ws_size is too small.
// ---------------------------------------------------------------------------
__global__ void wt2_kernel(const float* __restrict__ w, short* __restrict__ wt2) {
    int i = blockIdx.x * 256 + threadIdx.x;
    if (i < 9 * COUT * CIN) {
        int c = i & 63, o = (i >> 6) & 63, t = i >> 12;
        wt2[i] = f2bf(w[(o * CIN + c) * 9 + t]);
    }
}

__global__ __launch_bounds__(256) void pdconv_mfma_kernel(
    const float* __restrict__ in, const short* __restrict__ wt2,
    const float* __restrict__ rate_map, const float* __restrict__ bias,
    float* __restrict__ out)
{
    const int tid = threadIdx.x, wave = tid >> 6, lane = tid & 63;
    const int px = lane & 15, g = lane >> 4;
    const int cpx = gridDim.x >> 3;
    const int bid = (blockIdx.x & 7) * cpx + (blockIdx.x >> 3);
    const int base = bid * 64 + wave * 16;
    const int b = base / HW, pix0 = base - b * HW;
    const int y = pix0 / WW, x0 = pix0 - y * WW, x = x0 + px;
    const float rate = rate_map[base + px];
    const float fy = (float)y, fx = (float)x;
    f32x4 acc[4];
#pragma unroll
    for (int mt = 0; mt < 4; ++mt) acc[mt] = (f32x4){0.f, 0.f, 0.f, 0.f};
    const float* img  = in + (size_t)b * CIN * HW;
    const float* imgg = img + (size_t)g * 8 * HW;
#pragma unroll 1
    for (int t = 0; t < 9; ++t) {
        const int ky = t / 3, kx = t - 3 * ky;
        const float sy = fy + (float)(ky - 1) * rate;
        const float sx = fx + (float)(kx - 1) * rate;
        const float y0f = floorf(sy), x0f = floorf(sx);
        const float wy = sy - y0f, wx = sx - x0f;
        const int y0 = (int)y0f, x0i = (int)x0f, y1 = y0 + 1, x1 = x0i + 1;
        const float omwy = 1.0f - wy, omwx = 1.0f - wx;
        const float vy0 = (y0 >= 0 && y0 < HH) ? 1.0f : 0.0f;
        const float vy1 = (y1 >= 0 && y1 < HH) ? 1.0f : 0.0f;
        const float vx0 = (x0i >= 0 && x0i < WW) ? 1.0f : 0.0f;
        const float vx1 = (x1 >= 0 && x1 < WW) ? 1.0f : 0.0f;
        const float c00 = omwy * omwx * vy0 * vx0, c01 = omwy * wx * vy0 * vx1;
        const float c10 = wy * omwx * vy1 * vx0,  c11 = wy * wx * vy1 * vx1;
        const int cy0 = min(max(y0, 0), HH - 1), cy1 = min(max(y1, 0), HH - 1);
        const int cx0 = min(max(x0i, 0), WW - 1), cx1 = min(max(x1, 0), WW - 1);
        const int i00 = cy0 * WW + cx0, i01 = cy0 * WW + cx1;
        const int i10 = cy1 * WW + cx0, i11 = cy1 * WW + cx1;
#pragma unroll
        for (int ks = 0; ks < 2; ++ks) {
            bf16x8 wf[4];
#pragma unroll
            for (int mt = 0; mt < 4; ++mt)
                wf[mt] = *(const bf16x8*)(wt2 +
                          ((t * COUT + 16 * mt + px) * CIN + 32 * ks + 8 * g));
            float a[8];
#pragma unroll
            for (int j = 0; j < 8; ++j) {
                const float* ch = imgg + (size_t)(32 * ks + j) * HW;
                a[j] = c00 * ch[i00] + c01 * ch[i01] + c10 * ch[i10] + c11 * ch[i11];
            }
            union { bf16x8 v; short s[8]; } pf;
#pragma unroll
            for (int j = 0; j < 8; ++j) pf.s[j] = f2bf(a[j]);
#pragma unroll
            for (int mt = 0; mt < 4; ++mt)
                acc[mt] = __builtin_amdgcn_mfma_f32_16x16x32_bf16(
                              wf[mt], pf.v, acc[mt], 0, 0, 0);
        }
    }
    float* op = out + (size_t)b * COUT * HW + pix0 + px;
#pragma unroll
    for (int mt = 0; mt < 4; ++mt)
#pragma unroll
        for (int r = 0; r < 4; ++r) {
            const int o = 16 * mt + 4 * g + r;
            op[(size_t)o * HW] = acc[mt][r] + bias[o];
        }
}

extern "C" void kernel_launch(void* const* d_in, const int* in_sizes, int n_in,
                              void* d_out, int out_size, void* d_ws, size_t ws_size,
                              hipStream_t stream) {
    (void)in_sizes; (void)n_in; (void)out_size;
    const float* in   = (const float*)d_in[0];
    const float* w    = (const float*)d_in[1];
    const float* rm   = (const float*)d_in[2];
    const float* bias = (const float*)d_in[3];
    float* out = (float*)d_out;

    const size_t WTF_BYTES = 36864 * sizeof(short);                 // 73,728
    const size_t TIN_BYTES = (size_t)NB * HW * CIN * sizeof(short); // 13,107,200

    if (ws_size >= WTF_BYTES + TIN_BYTES) {
        short* wtf = (short*)d_ws;
        short* tin = (short*)((char*)d_ws + WTF_BYTES);
        hipLaunchKernelGGL(wtf_kernel, dim3(144), dim3(256), 0, stream, w, wtf);
        hipLaunchKernelGGL(tin_kernel, dim3((NB * HW) / 256), dim3(256),
                           0, stream, in, tin);
        const int nblocks = NB * 80 * 10;  // 3200: 2x16 tiles
        hipLaunchKernelGGL(pdconv_tile_kernel, dim3(nblocks), dim3(256), 0,
                           stream, tin, wtf, rm, bias, out);
    } else {
        short* wt2 = (short*)d_ws;   // 73,728 B
        hipLaunchKernelGGL(wt2_kernel, dim3(144), dim3(256), 0, stream, w, wt2);
        hipLaunchKernelGGL(pdconv_mfma_kernel, dim3((NB * HW) / 64), dim3(256),
                           0, stream, in, wt2, rm, bias, out);
    }
}

// Round 25
// 43.416 us; speedup vs baseline: 1.1138x; 1.1138x over previous
//
#include <hip/hip_runtime.h>
#include <hip/hip_bf16.h>

#define NB   4
#define CIN  64
#define COUT 64
#define HH   160
#define WW   160
#define HW   (HH * WW)

// halo tile: 2x16 output tile, rate in [1,3) =>
// rows 2rr-3 .. 2rr+4 (8), cols 16cc-3 .. 16cc+18 (22).
#define RT   8
#define CT   22
#define RS   72              // record stride in shorts (144 B: 64ch + 8 pad)
#define RSB  (RS * 2)        // record stride in bytes (144)
#define HIN_SHORTS (RT * CT * RS)   // 12672 shorts = 25344 B

typedef __attribute__((ext_vector_type(8))) short bf16x8;   // 8 bf16 = 4 VGPR
typedef __attribute__((ext_vector_type(4))) float f32x4;
typedef __attribute__((ext_vector_type(2))) float f32x2;
typedef __attribute__((ext_vector_type(4))) unsigned int u32x4;

static __device__ __forceinline__ short f2bf(float v) {
    return __builtin_bit_cast(short, __float2bfloat16(v));
}

// ---------------------------------------------------------------------------
// Pre-pass: weight [O][C][3][3] f32 -> wtf in exact A-fragment order:
// wtf[t][ks][mt][lane][j]; frag (t,ks,mt) = contiguous 1 KB, lane reads 16 B.
// (The input-transpose prepass is GONE — R25: halo staging now reads NCHW
// f32 directly, saving the 39 MB tin round-trip ≈ 6 µs + one dispatch.)
// ---------------------------------------------------------------------------
__global__ void wtf_kernel(const float* __restrict__ w, short* __restrict__ wtf) {
    int i = blockIdx.x * 256 + threadIdx.x;   // 9*2*4*64*8 = 36864
    if (i < 36864) {
        const int j  = i & 7;
        const int l  = (i >> 3) & 63;
        const int mt = (i >> 9) & 3;
        const int ks = (i >> 11) & 1;
        const int t  = i >> 12;
        const int o  = 16 * mt + (l & 15);
        const int c  = 32 * ks + 8 * (l >> 4) + j;
        wtf[i] = f2bf(w[(o * CIN + c) * 9 + t]);
    }
}

// Blend 8 channels (4 dwords of packed bf16 pairs) + 4 MFMA rank-updates.
static __device__ __forceinline__ void consume_tap(
    const u32x4 v00, const u32x4 v01, const u32x4 v10, const u32x4 v11,
    const float c00, const float c01, const float c10, const float c11,
    const bf16x8 wf0, const bf16x8 wf1, const bf16x8 wf2, const bf16x8 wf3,
    f32x4 acc[4])
{
    union { bf16x8 v; unsigned u[4]; } pf;
#pragma unroll
    for (int wd = 0; wd < 4; ++wd) {
        f32x2 s;
        {
            const unsigned u0 = v00[wd];
            const f32x2 xv = { __builtin_bit_cast(float, u0 << 16),
                               __builtin_bit_cast(float, u0 & 0xffff0000u) };
            s = c00 * xv;
        }
        {
            const unsigned u0 = v01[wd];
            const f32x2 xv = { __builtin_bit_cast(float, u0 << 16),
                               __builtin_bit_cast(float, u0 & 0xffff0000u) };
            s += c01 * xv;
        }
        {
            const unsigned u0 = v10[wd];
            const f32x2 xv = { __builtin_bit_cast(float, u0 << 16),
                               __builtin_bit_cast(float, u0 & 0xffff0000u) };
            s += c10 * xv;
        }
        {
            const unsigned u0 = v11[wd];
            const f32x2 xv = { __builtin_bit_cast(float, u0 << 16),
                               __builtin_bit_cast(float, u0 & 0xffff0000u) };
            s += c11 * xv;
        }
        unsigned r;
        asm("v_cvt_pk_bf16_f32 %0, %1, %2" : "=v"(r) : "v"(s.x), "v"(s.y));
        pf.u[wd] = r;
    }
    acc[0] = __builtin_amdgcn_mfma_f32_16x16x32_bf16(wf0, pf.v, acc[0], 0, 0, 0);
    acc[1] = __builtin_amdgcn_mfma_f32_16x16x32_bf16(wf1, pf.v, acc[1], 0, 0, 0);
    acc[2] = __builtin_amdgcn_mfma_f32_16x16x32_bf16(wf2, pf.v, acc[2], 0, 0, 0);
    acc[3] = __builtin_amdgcn_mfma_f32_16x16x32_bf16(wf3, pf.v, acc[3], 0, 0, 0);
}

// ---------------------------------------------------------------------------
// Main kernel (R23 structure + FUSED NCHW STAGING): block = 2x16 output
// tile, 4 waves = 2 rows x 2 K-halves, hoisted separable geometry
// (R23-verified). Halo staging reads the ORIGINAL NCHW f32 input directly:
// thread tid<176 owns record (ty,tx); its clamped (gy,gx) is loop-invariant;
// it walks 64 channels at stride HW (64 independent L3-hot dword loads,
// 22-thread row segments = 88 B contiguous) converting to bf16 into
// hin[rec][ch]. LDS b16 writes at 144 B lane stride (<=2-way = free).
// Eliminates the 39 MB tin prepass (~6 us) + one dispatch.
// ---------------------------------------------------------------------------
__global__ __launch_bounds__(256, 4) void pdconv_tile_kernel(
    const float* __restrict__ in,        // [B][CIN][H][W] f32 (original!)
    const short* __restrict__ wtf,       // frag-ordered weights bf16
    const float* __restrict__ rate_map,  // [B][1][H][W] f32
    const float* __restrict__ bias,      // [COUT] f32
    float* __restrict__ out)             // [B][COUT][H][W] f32
{
    __shared__ short hin[HIN_SHORTS];    // 25,344 B
    __shared__ float red[2][64][17];     // 8,704 B

    const int tid  = threadIdx.x;
    const int wave = tid >> 6;
    const int lane = tid & 63;
    const int px   = lane & 15;
    const int g    = lane >> 4;
    const int r    = wave >> 1;          // row within the 2-row tile
    const int th   = wave & 1;           // channel half (ks)

    // XCD-bijective swizzle (3200 % 8 == 0)
    const int cpx = gridDim.x >> 3;                     // 400
    const int bid = (blockIdx.x & 7) * cpx + (blockIdx.x >> 3);

    // bid -> (b, row-pair rr, col-block cc): 80 pairs x 10 col-blocks / image
    const int b   = bid / 800;
    const int rem = bid - b * 800;
    const int rr  = rem / 10;
    const int cc  = rem - rr * 10;
    const int oy  = 2 * rr - 3;
    const int ox  = 16 * cc - 3;

    // ---- fused staging: NCHW f32 -> LDS bf16 halo (edges clamped) ----
    if (tid < RT * CT) {
        const int ty = tid / CT;
        const int tx = tid - ty * CT;
        const int gy = min(max(oy + ty, 0), HH - 1);
        const int gx = min(max(ox + tx, 0), WW - 1);
        const float* src = in + (size_t)b * CIN * HW + gy * WW + gx;
        short* dst = hin + tid * RS;
#pragma unroll 16
        for (int c = 0; c < CIN; ++c)
            dst[c] = f2bf(src[(size_t)c * HW]);
    }

    // ---- per-wave output strip: row = 2rr + r, cols 16cc..16cc+15 ----
    const int row = 2 * rr + r;
    const int x   = 16 * cc + px;
    const float rate = rate_map[b * HW + row * WW + x];
    const float fy = (float)row, fx = (float)x;

    // ---- hoisted separable geometry (R23-verified incl. >=0 checks) ----
    float wy0v[3], wy1v[3];  int ryb[3];
#pragma unroll
    for (int ky = 0; ky < 3; ++ky) {
        const float sy  = fy + (float)(ky - 1) * rate;
        const float y0f = floorf(sy);
        const float wy  = sy - y0f;
        const int   y0  = (int)y0f;
        const float vy0 = (y0 >= 0 && y0 < HH) ? 1.0f : 0.0f;
        const float vy1 = (y0 + 1 >= 0 && y0 + 1 < HH) ? 1.0f : 0.0f;
        wy0v[ky] = (1.0f - wy) * vy0;
        wy1v[ky] = wy * vy1;
        ryb[ky]  = (y0 - oy) * (CT * RSB);               // tile-row byte offset
    }
    float wx0v[3], wx1v[3];  int txb[3];
#pragma unroll
    for (int kx = 0; kx < 3; ++kx) {
        const float sx  = fx + (float)(kx - 1) * rate;
        const float x0f = floorf(sx);
        const float wx  = sx - x0f;
        const int   x0  = (int)x0f;
        const float vx0 = (x0 >= 0 && x0 < WW) ? 1.0f : 0.0f;
        const float vx1 = (x0 + 1 >= 0 && x0 + 1 < WW) ? 1.0f : 0.0f;
        wx0v[kx] = (1.0f - wx) * vx0;
        wx1v[kx] = wx * vx1;
        txb[kx]  = (x0 - ox) * RSB;                      // tile-col byte offset
    }

    const int chan_off = 32 * th + 8 * g;                // shorts

    const short* wtb = wtf + lane * 8;                   // + frag*512

    f32x4 acc[4];
#pragma unroll
    for (int mt = 0; mt < 4; ++mt) acc[mt] = (f32x4){0.f, 0.f, 0.f, 0.f};

    __syncthreads();           // halo staged

    // per tap: 1 addr add + 4 coef muls + 4 ds_read_b128 + weights + MFMA
#define DO_TAP(T) do {                                                       \
    const int ky = (T) / 3, kx = (T) - 3 * ((T) / 3);   /* constants */      \
    const float c00 = wy0v[ky] * wx0v[kx];                                   \
    const float c01 = wy0v[ky] * wx1v[kx];                                   \
    const float c10 = wy1v[ky] * wx0v[kx];                                   \
    const float c11 = wy1v[ky] * wx1v[kx];                                   \
    const short* hk = (const short*)((const char*)hin + ryb[ky] + txb[kx])   \
                      + chan_off;                                            \
    const u32x4 v00 = *(const u32x4*)(hk);                                   \
    const u32x4 v01 = *(const u32x4*)(hk + RS);                              \
    const u32x4 v10 = *(const u32x4*)(hk + CT * RS);                         \
    const u32x4 v11 = *(const u32x4*)(hk + (CT + 1) * RS);                   \
    const short* wb = wtb + (size_t)(((T) * 2 + th) * 4) * 512;              \
    const bf16x8 wf0 = *(const bf16x8*)(wb);                                 \
    const bf16x8 wf1 = *(const bf16x8*)(wb + 512);                           \
    const bf16x8 wf2 = *(const bf16x8*)(wb + 1024);                          \
    const bf16x8 wf3 = *(const bf16x8*)(wb + 1536);                          \
    consume_tap(v00, v01, v10, v11, c00, c01, c10, c11,                      \
                wf0, wf1, wf2, wf3, acc);                                    \
} while (0)

    DO_TAP(0); DO_TAP(1); DO_TAP(2); DO_TAP(3); DO_TAP(4);
    DO_TAP(5); DO_TAP(6); DO_TAP(7); DO_TAP(8);
#undef DO_TAP

    // ---- channel-half reduction via dedicated red buffer ----
    if (th == 1) {
#pragma unroll
        for (int mt = 0; mt < 4; ++mt)
#pragma unroll
            for (int j = 0; j < 4; ++j)
                red[r][lane][4 * mt + j] = acc[mt][j];
    }
    __syncthreads();
    if (th == 0) {
        float* op = out + (size_t)b * COUT * HW + row * WW + 16 * cc + px;
#pragma unroll
        for (int mt = 0; mt < 4; ++mt) {
            const f32x4 bv = *(const f32x4*)(bias + 16 * mt + 4 * g);
#pragma unroll
            for (int j = 0; j < 4; ++j) {
                const int o = 16 * mt + 4 * g + j;
                op[(size_t)o * HW] = acc[mt][j] + red[r][lane][4 * mt + j]
                                   + bv[j];
            }
        }
    }
}

// ---------------------------------------------------------------------------
// Fallback (round-7 NCHW path) if ws_size is too small.
// ---------------------------------------------------------------------------
__global__ void wt2_kernel(const float* __restrict__ w, short* __restrict__ wt2) {
    int i = blockIdx.x * 256 + threadIdx.x;
    if (i < 9 * COUT * CIN) {
        int c = i & 63, o = (i >> 6) & 63, t = i >> 12;
        wt2[i] = f2bf(w[(o * CIN + c) * 9 + t]);
    }
}

__global__ __launch_bounds__(256) void pdconv_mfma_kernel(
    const float* __restrict__ in, const short* __restrict__ wt2,
    const float* __restrict__ rate_map, const float* __restrict__ bias,
    float* __restrict__ out)
{
    const int tid = threadIdx.x, wave = tid >> 6, lane = tid & 63;
    const int px = lane & 15, g = lane >> 4;
    const int cpx = gridDim.x >> 3;
    const int bid = (blockIdx.x & 7) * cpx + (blockIdx.x >> 3);
    const int base = bid * 64 + wave * 16;
    const int b = base / HW, pix0 = base - b * HW;
    const int y = pix0 / WW, x0 = pix0 - y * WW, x = x0 + px;
    const float rate = rate_map[base + px];
    const float fy = (float)y, fx = (float)x;
    f32x4 acc[4];
#pragma unroll
    for (int mt = 0; mt < 4; ++mt) acc[mt] = (f32x4){0.f, 0.f, 0.f, 0.f};
    const float* img  = in + (size_t)b * CIN * HW;
    const float* imgg = img + (size_t)g * 8 * HW;
#pragma unroll 1
    for (int t = 0; t < 9; ++t) {
        const int ky = t / 3, kx = t - 3 * ky;
        const float sy = fy + (float)(ky - 1) * rate;
        const float sx = fx + (float)(kx - 1) * rate;
        const float y0f = floorf(sy), x0f = floorf(sx);
        const float wy = sy - y0f, wx = sx - x0f;
        const int y0 = (int)y0f, x0i = (int)x0f, y1 = y0 + 1, x1 = x0i + 1;
        const float omwy = 1.0f - wy, omwx = 1.0f - wx;
        const float vy0 = (y0 >= 0 && y0 < HH) ? 1.0f : 0.0f;
        const float vy1 = (y1 >= 0 && y1 < HH) ? 1.0f : 0.0f;
        const float vx0 = (x0i >= 0 && x0i < WW) ? 1.0f : 0.0f;
        const float vx1 = (x1 >= 0 && x1 < WW) ? 1.0f : 0.0f;
        const float c00 = omwy * omwx * vy0 * vx0, c01 = omwy * wx * vy0 * vx1;
        const float c10 = wy * omwx * vy1 * vx0,  c11 = wy * wx * vy1 * vx1;
        const int cy0 = min(max(y0, 0), HH - 1), cy1 = min(max(y1, 0), HH - 1);
        const int cx0 = min(max(x0i, 0), WW - 1), cx1 = min(max(x1, 0), WW - 1);
        const int i00 = cy0 * WW + cx0, i01 = cy0 * WW + cx1;
        const int i10 = cy1 * WW + cx0, i11 = cy1 * WW + cx1;
#pragma unroll
        for (int ks = 0; ks < 2; ++ks) {
            bf16x8 wf[4];
#pragma unroll
            for (int mt = 0; mt < 4; ++mt)
                wf[mt] = *(const bf16x8*)(wt2 +
                          ((t * COUT + 16 * mt + px) * CIN + 32 * ks + 8 * g));
            float a[8];
#pragma unroll
            for (int j = 0; j < 8; ++j) {
                const float* ch = imgg + (size_t)(32 * ks + j) * HW;
                a[j] = c00 * ch[i00] + c01 * ch[i01] + c10 * ch[i10] + c11 * ch[i11];
            }
            union { bf16x8 v; short s[8]; } pf;
#pragma unroll
            for (int j = 0; j < 8; ++j) pf.s[j] = f2bf(a[j]);
#pragma unroll
            for (int mt = 0; mt < 4; ++mt)
                acc[mt] = __builtin_amdgcn_mfma_f32_16x16x32_bf16(
                              wf[mt], pf.v, acc[mt], 0, 0, 0);
        }
    }
    float* op = out + (size_t)b * COUT * HW + pix0 + px;
#pragma unroll
    for (int mt = 0; mt < 4; ++mt)
#pragma unroll
        for (int r = 0; r < 4; ++r) {
            const int o = 16 * mt + 4 * g + r;
            op[(size_t)o * HW] = acc[mt][r] + bias[o];
        }
}

extern "C" void kernel_launch(void* const* d_in, const int* in_sizes, int n_in,
                              void* d_out, int out_size, void* d_ws, size_t ws_size,
                              hipStream_t stream) {
    (void)in_sizes; (void)n_in; (void)out_size;
    const float* in   = (const float*)d_in[0];
    const float* w    = (const float*)d_in[1];
    const float* rm   = (const float*)d_in[2];
    const float* bias = (const float*)d_in[3];
    float* out = (float*)d_out;

    const size_t WTF_BYTES = 36864 * sizeof(short);   // 73,728

    if (ws_size >= WTF_BYTES) {
        short* wtf = (short*)d_ws;
        hipLaunchKernelGGL(wtf_kernel, dim3(144), dim3(256), 0, stream, w, wtf);
        const int nblocks = NB * 80 * 10;  // 3200: 2x16 tiles
        hipLaunchKernelGGL(pdconv_tile_kernel, dim3(nblocks), dim3(256), 0,
                           stream, in, wtf, rm, bias, out);
    } else {
        short* wt2 = (short*)d_ws;   // 73,728 B
        hipLaunchKernelGGL(wt2_kernel, dim3(144), dim3(256), 0, stream, w, wt2);
        hipLaunchKernelGGL(pdconv_mfma_kernel, dim3((NB * HW) / 64), dim3(256),
                           0, stream, in, wt2, rm, bias, out);
    }
}